// Round 7
// baseline (206.692 us; speedup 1.0000x reference)
//
#include <hip/hip_runtime.h>

// NavierStokesLossMAC: B=8, H=W=1024
//   d_in[0] v_old (B,2,H,W) f32 | d_in[1] v_new (B,2,H,W) f32
//   d_in[2] p_new (B,1,H,W) f32 | d_in[3] mask  (B,1,H,W) i32
// out: (B,) f32
//
// R7 = R6 rolling-window (ROWS=7, y-reuse in registers, minimal request
// traffic) + x-split for parallelism: block = 128 threads x 512 cols.
// R6 post-mortem: FETCH halved to 119MB but time pinned at 78us with
// occupancy 19% (~6 waves/CU) -- lost MLP ate the traffic win. R4 had MLP
// (65% occ) but 2x request traffic: same 78us. This round: both at once.
// Grid 2336 blocks x 2 waves -> 8 blocks/CU capacity, finer tail.
// No __launch_bounds__ min-waves (R5: (256,4) cap -> 253MB scratch spill).
// Stage 2: plain stores + per-batch reduce (R2: same-line atomicAdd
// serializes cross-XCD write-backs, ~15ns each).

#define NS_H 1024
#define NS_W 1024
#define ROWS 7
#define STRIPS ((NS_H - 2) / ROWS)   // 146 * 7 = 1022 exactly
#define XHALF 512
#define PARTS_PER_B (STRIPS * 2)     // 292

__device__ __forceinline__ float4 ld4(const float* p) { return *(const float4*)p; }
__device__ __forceinline__ float4 avg4(float4 a, float4 b) {
    return make_float4(0.5f*(a.x+b.x), 0.5f*(a.y+b.y), 0.5f*(a.z+b.z), 0.5f*(a.w+b.w));
}
__device__ __forceinline__ float4 sub4(float4 a, float4 b) {
    return make_float4(a.x-b.x, a.y-b.y, a.z-b.z, a.w-b.w);
}

__global__ __launch_bounds__(128) void ns_loss_partial(
    const float* __restrict__ v_old,
    const float* __restrict__ v_new,
    const float* __restrict__ p,
    const int*   __restrict__ mask,
    float* __restrict__ ws)
{
    const int blk = blockIdx.x;
    const int b   = blk / PARTS_PER_B;
    const int t2  = blk % PARTS_PER_B;
    const int rb  = t2 >> 1;
    const int xh  = t2 & 1;
    const int y0  = 1 + rb * ROWS;

    const size_t hw = (size_t)NS_H * NS_W;
    const float* uo = v_old + (size_t)b * 2 * hw;
    const float* wo = uo + hw;
    const float* un = v_new + (size_t)b * 2 * hw;
    const float* wn = un + hw;
    const float* pb = p    + (size_t)b * hw;
    const int*   mb = mask + (size_t)b * hw;

    const int tid = (int)threadIdx.x;
    const int x0  = xh * XHALF + tid * 4;
    // right edge load at x0+4: OOB only for x0=1020 on the very last row of
    // the array (feeds masked x=1023 anyway) -> guard it.
    const bool has_r = (x0 + 4 < NS_W);
    // left edge at x0-1: always in-bounds memory (y>=1 => index >= NS_W-1);
    // value only feeds masked x=0 when x0==0.

    // ---- prologue: row y0-1 (y-minus) and row y0 (center) ----
    const int r_m = (y0 - 1) * NS_W;
    const int r_c = y0 * NS_W;

    float4 a, bb, c, d;
    a = ld4(un + r_m + x0); bb = ld4(uo + r_m + x0);
    c = ld4(wn + r_m + x0); d  = ld4(wo + r_m + x0);
    float4 u_m = avg4(a, bb), w_m = avg4(c, d);

    a = ld4(un + r_c + x0); bb = ld4(uo + r_c + x0);
    c = ld4(wn + r_c + x0); d  = ld4(wo + r_c + x0);
    float4 u_c = avg4(a, bb), w_c = avg4(c, d);
    float4 du_c = sub4(a, bb), dw_c = sub4(c, d);

    float ul_c = 0.5f * (un[r_c + x0 - 1] + uo[r_c + x0 - 1]);
    float wl_c = 0.5f * (wn[r_c + x0 - 1] + wo[r_c + x0 - 1]);
    float ur_c = 0.f, wr_c = 0.f;
    if (has_r) {
        ur_c = 0.5f * (un[r_c + x0 + 4] + uo[r_c + x0 + 4]);
        wr_c = 0.5f * (wn[r_c + x0 + 4] + wo[r_c + x0 + 4]);
    }
    float4 p_m = ld4(pb + r_m + x0);

    float acc = 0.f;

    #pragma unroll
    for (int r = 0; r < ROWS; ++r) {
        const int rc = (y0 + r) * NS_W;
        const int rp = rc + NS_W;

        a = ld4(un + rp + x0); bb = ld4(uo + rp + x0);
        c = ld4(wn + rp + x0); d  = ld4(wo + rp + x0);
        float4 pc4 = ld4(pb + rc + x0);
        int4   m4  = *(const int4*)(mb + rc + x0);
        float  pl  = pb[rc + x0 - 1];

        float ul_p = 0.5f * (un[rp + x0 - 1] + uo[rp + x0 - 1]);
        float wl_p = 0.5f * (wn[rp + x0 - 1] + wo[rp + x0 - 1]);
        float ur_p = 0.f, wr_p = 0.f;
        if (has_r) {
            ur_p = 0.5f * (un[rp + x0 + 4] + uo[rp + x0 + 4]);
            wr_p = 0.5f * (wn[rp + x0 + 4] + wo[rp + x0 + 4]);
        }

        float4 u_p = avg4(a, bb), w_p = avg4(c, d);
        float4 du_p = sub4(a, bb), dw_p = sub4(c, d);

        // ---- compute row y0+r ----
        const float uc[6]  = {ul_c, u_c.x, u_c.y, u_c.z, u_c.w, ur_c};
        const float wcv[6] = {wl_c, w_c.x, w_c.y, w_c.z, w_c.w, wr_c};
        const float uym[4] = {u_m.x, u_m.y, u_m.z, u_m.w};
        const float uyp[4] = {u_p.x, u_p.y, u_p.z, u_p.w};
        const float wym[4] = {w_m.x, w_m.y, w_m.z, w_m.w};
        const float wyp[4] = {w_p.x, w_p.y, w_p.z, w_p.w};
        const float du[4]  = {du_c.x, du_c.y, du_c.z, du_c.w};
        const float dw[4]  = {dw_c.x, dw_c.y, dw_c.z, dw_c.w};
        const float pcv[5] = {pl, pc4.x, pc4.y, pc4.z, pc4.w};
        const float pym[4] = {p_m.x, p_m.y, p_m.z, p_m.w};
        const int   mm[4]  = {m4.x, m4.y, m4.z, m4.w};

        #pragma unroll
        for (int j = 0; j < 4; ++j) {
            const int x = x0 + j;
            const float m = (x >= 1 && x <= NS_W - 2) ? (float)mm[j] : 0.f;

            const float u_cc = uc[j+1],  u_xm = uc[j],  u_xp = uc[j+2];
            const float w_cc = wcv[j+1], w_xm = wcv[j], w_xp = wcv[j+2];

            float res_x =
                dw[j] * 0.25f
              + w_cc * 0.5f * (w_xp - w_xm)
              + 0.5f * ( 0.5f * (u_cc + u_xm) * (w_cc   - wym[j])
                       + 0.5f * (u_cc + u_xp) * (wyp[j] - w_cc  ) )
              + (pcv[j+1] - pcv[j])
              - 0.1f * (w_xm + w_xp + wym[j] + wyp[j] - 4.f * w_cc);

            float res_y =
                du[j] * 0.25f
              + u_cc * 0.5f * (uyp[j] - uym[j])
              + 0.5f * ( 0.5f * (w_cc + wym[j]) * (u_cc - u_xm)
                       + 0.5f * (w_cc + wyp[j]) * (u_xp - u_cc) )
              + (pcv[j+1] - pym[j])
              - 0.1f * (u_xm + u_xp + uym[j] + uyp[j] - 4.f * u_cc);

            acc += m * (res_x * res_x + res_y * res_y);
        }

        // ---- roll the window ----
        u_m = u_c;  u_c = u_p;  ul_c = ul_p;  ur_c = ur_p;
        w_m = w_c;  w_c = w_p;  wl_c = wl_p;  wr_c = wr_p;
        du_c = du_p; dw_c = dw_p;
        p_m = pc4;
    }

    // ---- block reduction: wave shuffle -> 8B LDS -> one plain store ----
    #pragma unroll
    for (int off = 32; off > 0; off >>= 1)
        acc += __shfl_down(acc, off);

    __shared__ float smem[2];
    const int lane = tid & 63;
    const int wid  = tid >> 6;
    if (lane == 0) smem[wid] = acc;
    __syncthreads();

    if (tid == 0)
        ws[blk] = smem[0] + smem[1];
}

__global__ __launch_bounds__(256) void ns_loss_reduce(
    const float* __restrict__ ws, float* __restrict__ out)
{
    const int b = blockIdx.x;
    float acc = 0.f;
    for (int i = threadIdx.x; i < PARTS_PER_B; i += 256)
        acc += ws[b * PARTS_PER_B + i];

    #pragma unroll
    for (int off = 32; off > 0; off >>= 1)
        acc += __shfl_down(acc, off);

    __shared__ float smem[4];
    const int lane = threadIdx.x & 63;
    const int wid  = threadIdx.x >> 6;
    if (lane == 0) smem[wid] = acc;
    __syncthreads();

    if (threadIdx.x == 0) {
        const float inv = 1.0f / ((float)(NS_H - 2) * (float)(NS_W - 2));
        out[b] = (smem[0] + smem[1] + smem[2] + smem[3]) * inv;
    }
}

extern "C" void kernel_launch(void* const* d_in, const int* in_sizes, int n_in,
                              void* d_out, int out_size, void* d_ws, size_t ws_size,
                              hipStream_t stream) {
    const float* v_old = (const float*)d_in[0];
    const float* v_new = (const float*)d_in[1];
    const float* p_new = (const float*)d_in[2];
    const int*   msk   = (const int*)d_in[3];
    float* out = (float*)d_out;
    float* ws  = (float*)d_ws;

    const int B = out_size;   // 8

    ns_loss_partial<<<dim3(B * PARTS_PER_B), dim3(128), 0, stream>>>(v_old, v_new, p_new, msk, ws);
    ns_loss_reduce<<<dim3(B), dim3(256), 0, stream>>>(ws, out);
}

// Round 8
// 200.412 us; speedup vs baseline: 1.0313x; 1.0313x over previous
//
#include <hip/hip_runtime.h>

// NavierStokesLossMAC: B=8, H=W=1024
//   d_in[0] v_old (B,2,H,W) f32 | d_in[1] v_new (B,2,H,W) f32
//   d_in[2] p_new (B,1,H,W) f32 | d_in[3] mask  (B,1,H,W) i32
// out: (B,) f32
//
// R8: VMEM-instruction minimization. R3/R4/R6/R7 all pinned at ~78us while
// HBM bytes varied 2x and occupancy 3.5x -> neither is the limit. R4's
// wave-VMEM-instr count (~780k, ~60cyc/instr/CU) reproduces 78us; R7's
// occupancy integral shows ~600cyc/load (serialized). So: fewest possible
// VMEM instrs + real per-wave MLP.
//  * 2 rows per 256-thr block, straight-line: 21 float4 loads/thread for
//    8 outputs (2.6 instr/output vs R4's 6). No scalar edge sweeps (each
//    scalar instr costs the TA like a float4: 64 addresses).
//  * x-edges via __shfl within wave + lane-predicated seam loads (1 line).
//  * __launch_bounds__(256,3): 170-VGPR budget so the compiler keeps loads
//    in flight instead of register-minimizing to 36 like R4. (R5 lesson:
//    (256,4)=64-reg cap spilled 253MB; est. live here ~135 < 170.)
// Stage 2: plain ws stores + 8-block reduce (R2: same-line atomicAdd
// serializes cross-XCD write-backs).

#define NS_H 1024
#define NS_W 1024
#define RPB 2                         // rows per block
#define PAIRS ((NS_H - 2) / RPB)      // 511 row-pairs, exact
#define PARTS_PER_B PAIRS

__device__ __forceinline__ float4 ld4(const float* p) { return *(const float4*)p; }
__device__ __forceinline__ float4 avg4(float4 a, float4 b) {
    return make_float4(0.5f*(a.x+b.x), 0.5f*(a.y+b.y), 0.5f*(a.z+b.z), 0.5f*(a.w+b.w));
}
__device__ __forceinline__ float4 sub4(float4 a, float4 b) {
    return make_float4(a.x-b.x, a.y-b.y, a.z-b.z, a.w-b.w);
}

__global__ __launch_bounds__(256, 3) void ns_loss_partial(
    const float* __restrict__ v_old,
    const float* __restrict__ v_new,
    const float* __restrict__ p,
    const int*   __restrict__ mask,
    float* __restrict__ ws)
{
    const int blk = blockIdx.x;
    const int b   = blk / PAIRS;
    const int pr  = blk % PAIRS;
    const int y   = 1 + pr * RPB;         // rows y and y+1 computed here

    const size_t hw = (size_t)NS_H * NS_W;
    const float* uo = v_old + (size_t)b * 2 * hw;
    const float* wo = uo + hw;
    const float* un = v_new + (size_t)b * 2 * hw;
    const float* wn = un + hw;
    const float* pb = p    + (size_t)b * hw;
    const int*   mb = mask + (size_t)b * hw;

    const int tid  = (int)threadIdx.x;
    const int lane = tid & 63;
    const int x0   = tid * 4;
    const bool has_r = (x0 + 4 < NS_W);   // false only for x0==1020 (feeds masked x=1023)
    const bool seamL = (lane == 0) && (x0 > 0);
    const bool seamR = (lane == 63) && has_r;

    const int rm  = (y - 1) * NS_W;
    const int rc  = y * NS_W;
    const int rp  = rc + NS_W;
    const int rpp = rp + NS_W;

    // ---- 21 float4 loads, all independent ----
    float4 un_m = ld4(un + rm  + x0), uo_m = ld4(uo + rm  + x0);
    float4 un_c = ld4(un + rc  + x0), uo_c = ld4(uo + rc  + x0);
    float4 un_p = ld4(un + rp  + x0), uo_p = ld4(uo + rp  + x0);
    float4 un_q = ld4(un + rpp + x0), uo_q = ld4(uo + rpp + x0);
    float4 wn_m = ld4(wn + rm  + x0), wo_m = ld4(wo + rm  + x0);
    float4 wn_c = ld4(wn + rc  + x0), wo_c = ld4(wo + rc  + x0);
    float4 wn_p = ld4(wn + rp  + x0), wo_p = ld4(wo + rp  + x0);
    float4 wn_q = ld4(wn + rpp + x0), wo_q = ld4(wo + rpp + x0);
    float4 p_m4 = ld4(pb + rm + x0);
    float4 p_c4 = ld4(pb + rc + x0);
    float4 p_p4 = ld4(pb + rp + x0);
    int4   m_c4 = *(const int4*)(mb + rc + x0);
    int4   m_p4 = *(const int4*)(mb + rp + x0);

    // ---- time-averaged fields & time diffs ----
    float4 u_m = avg4(un_m, uo_m), u_c = avg4(un_c, uo_c);
    float4 u_p = avg4(un_p, uo_p), u_q = avg4(un_q, uo_q);
    float4 w_m = avg4(wn_m, wo_m), w_c = avg4(wn_c, wo_c);
    float4 w_p = avg4(wn_p, wo_p), w_q = avg4(wn_q, wo_q);
    float4 du_c = sub4(un_c, uo_c), du_p = sub4(un_p, uo_p);
    float4 dw_c = sub4(wn_c, wo_c), dw_p = sub4(wn_p, wo_p);

    // ---- x-edges via intra-wave shuffle; seam lanes via 1-line loads ----
    float ul_c = __shfl_up(u_c.w, 1), wl_c = __shfl_up(w_c.w, 1);
    float ul_p = __shfl_up(u_p.w, 1), wl_p = __shfl_up(w_p.w, 1);
    float pl_c = __shfl_up(p_c4.w, 1), pl_p = __shfl_up(p_p4.w, 1);
    if (seamL) {
        ul_c = 0.5f * (un[rc + x0 - 1] + uo[rc + x0 - 1]);
        wl_c = 0.5f * (wn[rc + x0 - 1] + wo[rc + x0 - 1]);
        ul_p = 0.5f * (un[rp + x0 - 1] + uo[rp + x0 - 1]);
        wl_p = 0.5f * (wn[rp + x0 - 1] + wo[rp + x0 - 1]);
        pl_c = pb[rc + x0 - 1];
        pl_p = pb[rp + x0 - 1];
    }
    float ur_c = __shfl_down(u_c.x, 1), wr_c = __shfl_down(w_c.x, 1);
    float ur_p = __shfl_down(u_p.x, 1), wr_p = __shfl_down(w_p.x, 1);
    if (seamR) {
        ur_c = 0.5f * (un[rc + x0 + 4] + uo[rc + x0 + 4]);
        wr_c = 0.5f * (wn[rc + x0 + 4] + wo[rc + x0 + 4]);
        ur_p = 0.5f * (un[rp + x0 + 4] + uo[rp + x0 + 4]);
        wr_p = 0.5f * (wn[rp + x0 + 4] + wo[rp + x0 + 4]);
    }
    if (!has_r) { ur_c = 0.f; wr_c = 0.f; ur_p = 0.f; wr_p = 0.f; }  // feeds masked x=1023

    float acc = 0.f;

    // ---- row yc: y- = row m, y+ = row p ----
    {
        const float uc[6]  = {ul_c, u_c.x, u_c.y, u_c.z, u_c.w, ur_c};
        const float wcv[6] = {wl_c, w_c.x, w_c.y, w_c.z, w_c.w, wr_c};
        const float uym[4] = {u_m.x, u_m.y, u_m.z, u_m.w};
        const float uyp[4] = {u_p.x, u_p.y, u_p.z, u_p.w};
        const float wym[4] = {w_m.x, w_m.y, w_m.z, w_m.w};
        const float wyp[4] = {w_p.x, w_p.y, w_p.z, w_p.w};
        const float du[4]  = {du_c.x, du_c.y, du_c.z, du_c.w};
        const float dw[4]  = {dw_c.x, dw_c.y, dw_c.z, dw_c.w};
        const float pcv[5] = {pl_c, p_c4.x, p_c4.y, p_c4.z, p_c4.w};
        const float pym[4] = {p_m4.x, p_m4.y, p_m4.z, p_m4.w};
        const int   mm[4]  = {m_c4.x, m_c4.y, m_c4.z, m_c4.w};

        #pragma unroll
        for (int j = 0; j < 4; ++j) {
            const int x = x0 + j;
            const float m = (x >= 1 && x <= NS_W - 2) ? (float)mm[j] : 0.f;
            const float u_cc = uc[j+1],  u_xm = uc[j],  u_xp = uc[j+2];
            const float w_cc = wcv[j+1], w_xm = wcv[j], w_xp = wcv[j+2];

            float res_x =
                dw[j] * 0.25f
              + w_cc * 0.5f * (w_xp - w_xm)
              + 0.5f * ( 0.5f * (u_cc + u_xm) * (w_cc   - wym[j])
                       + 0.5f * (u_cc + u_xp) * (wyp[j] - w_cc  ) )
              + (pcv[j+1] - pcv[j])
              - 0.1f * (w_xm + w_xp + wym[j] + wyp[j] - 4.f * w_cc);

            float res_y =
                du[j] * 0.25f
              + u_cc * 0.5f * (uyp[j] - uym[j])
              + 0.5f * ( 0.5f * (w_cc + wym[j]) * (u_cc - u_xm)
                       + 0.5f * (w_cc + wyp[j]) * (u_xp - u_cc) )
              + (pcv[j+1] - pym[j])
              - 0.1f * (u_xm + u_xp + uym[j] + uyp[j] - 4.f * u_cc);

            acc += m * (res_x * res_x + res_y * res_y);
        }
    }

    // ---- row yp: y- = row c, y+ = row q ----
    {
        const float uc[6]  = {ul_p, u_p.x, u_p.y, u_p.z, u_p.w, ur_p};
        const float wcv[6] = {wl_p, w_p.x, w_p.y, w_p.z, w_p.w, wr_p};
        const float uym[4] = {u_c.x, u_c.y, u_c.z, u_c.w};
        const float uyp[4] = {u_q.x, u_q.y, u_q.z, u_q.w};
        const float wym[4] = {w_c.x, w_c.y, w_c.z, w_c.w};
        const float wyp[4] = {w_q.x, w_q.y, w_q.z, w_q.w};
        const float du[4]  = {du_p.x, du_p.y, du_p.z, du_p.w};
        const float dw[4]  = {dw_p.x, dw_p.y, dw_p.z, dw_p.w};
        const float pcv[5] = {pl_p, p_p4.x, p_p4.y, p_p4.z, p_p4.w};
        const float pym[4] = {p_c4.x, p_c4.y, p_c4.z, p_c4.w};
        const int   mm[4]  = {m_p4.x, m_p4.y, m_p4.z, m_p4.w};

        #pragma unroll
        for (int j = 0; j < 4; ++j) {
            const int x = x0 + j;
            const float m = (x >= 1 && x <= NS_W - 2) ? (float)mm[j] : 0.f;
            const float u_cc = uc[j+1],  u_xm = uc[j],  u_xp = uc[j+2];
            const float w_cc = wcv[j+1], w_xm = wcv[j], w_xp = wcv[j+2];

            float res_x =
                dw[j] * 0.25f
              + w_cc * 0.5f * (w_xp - w_xm)
              + 0.5f * ( 0.5f * (u_cc + u_xm) * (w_cc   - wym[j])
                       + 0.5f * (u_cc + u_xp) * (wyp[j] - w_cc  ) )
              + (pcv[j+1] - pcv[j])
              - 0.1f * (w_xm + w_xp + wym[j] + wyp[j] - 4.f * w_cc);

            float res_y =
                du[j] * 0.25f
              + u_cc * 0.5f * (uyp[j] - uym[j])
              + 0.5f * ( 0.5f * (w_cc + wym[j]) * (u_cc - u_xm)
                       + 0.5f * (w_cc + wyp[j]) * (u_xp - u_cc) )
              + (pcv[j+1] - pym[j])
              - 0.1f * (u_xm + u_xp + uym[j] + uyp[j] - 4.f * u_cc);

            acc += m * (res_x * res_x + res_y * res_y);
        }
    }

    // ---- block reduction: wave shuffle -> 16B LDS -> one plain store ----
    #pragma unroll
    for (int off = 32; off > 0; off >>= 1)
        acc += __shfl_down(acc, off);

    __shared__ float smem[4];
    const int wid = tid >> 6;
    if (lane == 0) smem[wid] = acc;
    __syncthreads();

    if (tid == 0)
        ws[blk] = smem[0] + smem[1] + smem[2] + smem[3];
}

__global__ __launch_bounds__(256) void ns_loss_reduce(
    const float* __restrict__ ws, float* __restrict__ out)
{
    const int b = blockIdx.x;
    float acc = 0.f;
    for (int i = threadIdx.x; i < PARTS_PER_B; i += 256)
        acc += ws[b * PARTS_PER_B + i];

    #pragma unroll
    for (int off = 32; off > 0; off >>= 1)
        acc += __shfl_down(acc, off);

    __shared__ float smem[4];
    const int lane = threadIdx.x & 63;
    const int wid  = threadIdx.x >> 6;
    if (lane == 0) smem[wid] = acc;
    __syncthreads();

    if (threadIdx.x == 0) {
        const float inv = 1.0f / ((float)(NS_H - 2) * (float)(NS_W - 2));
        out[b] = (smem[0] + smem[1] + smem[2] + smem[3]) * inv;
    }
}

extern "C" void kernel_launch(void* const* d_in, const int* in_sizes, int n_in,
                              void* d_out, int out_size, void* d_ws, size_t ws_size,
                              hipStream_t stream) {
    const float* v_old = (const float*)d_in[0];
    const float* v_new = (const float*)d_in[1];
    const float* p_new = (const float*)d_in[2];
    const int*   msk   = (const int*)d_in[3];
    float* out = (float*)d_out;
    float* ws  = (float*)d_ws;

    const int B = out_size;   // 8

    ns_loss_partial<<<dim3(B * PAIRS), dim3(256), 0, stream>>>(v_old, v_new, p_new, msk, ws);
    ns_loss_reduce<<<dim3(B), dim3(256), 0, stream>>>(ws, out);
}